// Round 9
// baseline (62.482 us; speedup 1.0000x reference)
//
#include <hip/hip_runtime.h>

namespace {
constexpr int kH       = 16;
constexpr int kS       = 2048;
constexpr int kD       = 64;
constexpr int kNpos    = 64;
constexpr int kHid     = 1024;  // H*D
constexpr int kChunk   = 256;   // 64 lanes * 4 floats
constexpr int kNChunks = kS / kChunk;    // 8
constexpr int kRowsPerBlock = 16;        // 4 waves * 4 rows
}

typedef float vfloat4 __attribute__((ext_vector_type(4)));

__device__ __forceinline__ float dot4f(float4 a, float qx, float qy, float qz, float qw) {
    return fmaf(a.x, qx, fmaf(a.y, qy, fmaf(a.z, qz, a.w * qw)));
}

template <int CTRL, int ROWM>
__device__ __forceinline__ float dpp_add(float v) {
    int t = __builtin_amdgcn_update_dpp(0, __float_as_int(v), CTRL, ROWM, 0xf, true);
    return v + __int_as_float(t);
}

// 64-lane inclusive prefix sum, pure VALU (classic GCN DPP scan).
__device__ __forceinline__ float wave_incl_scan(float v) {
    v = dpp_add<0x111, 0xf>(v);  // row_shr:1
    v = dpp_add<0x112, 0xf>(v);  // row_shr:2
    v = dpp_add<0x114, 0xf>(v);  // row_shr:4
    v = dpp_add<0x118, 0xf>(v);  // row_shr:8
    v = dpp_add<0x142, 0xa>(v);  // row_bcast15 -> rows 1,3
    v = dpp_add<0x143, 0xc>(v);  // row_bcast31 -> rows 2,3
    return v;
}

__device__ __forceinline__ float bcast_lane(float v, int l) {
    return __int_as_float(__builtin_amdgcn_readlane(__float_as_int(v), l));
}

__device__ __forceinline__ float wave_sum(float v) {
    return bcast_lane(wave_incl_scan(v), 63);
}

__device__ __forceinline__ void nt_store4(float* p, float a, float b, float c, float d) {
    vfloat4 v = {a, b, c, d};
    __builtin_nontemporal_store(v, reinterpret_cast<vfloat4*>(p));
}
__device__ __forceinline__ vfloat4 nt_load4(const float* p) {
    return __builtin_nontemporal_load(reinterpret_cast<const vfloat4*>(p));
}

__device__ __forceinline__ float sigm(float v) {
    return 1.0f / (1.0f + __expf(-v));
}

// Interpolate one position value against the lane-held logits table.
__device__ __forceinline__ float interp1(float acc, float pin) {
    float pc = fminf(pin, 63.0f);
    float fl = floorf(pc);
    float w  = pc - fl;
    int  fi  = (int)fl;
    int  ni  = (fi < kNpos - 1) ? fi + 1 : kNpos - 1;
    float lf = __shfl(acc, fi);
    float ln = __shfl(acc, ni);
    return fmaf(w, ln - lf, lf);   // == lf when w==0
}

// ---------------- Kernel A: pure nt-write fill of chunks 0..6 ----------------
// Per row: fill = dot(q_row, pe[h][63]) (DPP reduce), then 28 unrolled
// nt stores per wave. 229 MB pure write stream -> DRAM never turns around.
__global__ __launch_bounds__(256) void cope_fill_kernel(
    const float* __restrict__ query,
    const float* __restrict__ pos_emb,
    float* __restrict__ out)
{
    const int t    = threadIdx.x;
    const int lane = t & 63;
    const int wid  = t >> 6;
    const int row_base = blockIdx.x * kRowsPerBlock;
    const int h        = row_base >> 11;
    const int wrow = __builtin_amdgcn_readfirstlane(row_base + wid * 4);

    // pe[h][63][lane] — 256 B per head, L2-hot.
    const float pe63 = pos_emb[(size_t)(kNpos - 1) * kHid + h * kD + lane];

    const float* qrow = query + (size_t)wrow * kD;
    const float f0 = wave_sum(qrow[0 * kD + lane] * pe63);
    const float f1 = wave_sum(qrow[1 * kD + lane] * pe63);
    const float f2 = wave_sum(qrow[2 * kD + lane] * pe63);
    const float f3 = wave_sum(qrow[3 * kD + lane] * pe63);

    float* orow = out + (size_t)wrow * kS;
    #pragma unroll
    for (int j = 0; j < kNChunks - 1; ++j) {
        const int off = j * kChunk + lane * 4;
        nt_store4(orow + 0 * kS + off, f0, f0, f0, f0);
        nt_store4(orow + 1 * kS + off, f1, f1, f1, f1);
        nt_store4(orow + 2 * kS + off, f2, f2, f2, f2);
        nt_store4(orow + 3 * kS + off, f3, f3, f3, f3);
    }
}

// ---------------- Kernel B: scan + interpolate the rightmost chunk ----------
// Runs after the fill (same stream). Overwrites leftward (rare) while the
// cumsum hasn't clamped — correct for any data.
__device__ __forceinline__ void scan_row(const float* __restrict__ arow,
                                         float* __restrict__ orow,
                                         float acc, vfloat4 x0, int lane) {
    float running = 0.0f;
    vfloat4 x = x0;
    for (int c = kNChunks - 1; c >= 0; --c) {
        if (c != kNChunks - 1)
            x = nt_load4(arow + c * kChunk + lane * 4);
        float g0 = sigm(x.x), g1 = sigm(x.y);
        float g2 = sigm(x.z), g3 = sigm(x.w);

        float e3 = g3;
        float e2 = e3 + g2;
        float e1 = e2 + g1;
        float e0 = e1 + g0;          // lane total

        float incl  = wave_incl_scan(e0);
        float total = bcast_lane(incl, 63);
        float sfx   = running + (total - incl);

        float r0 = interp1(acc, sfx + e0);
        float r1 = interp1(acc, sfx + e1);
        float r2 = interp1(acc, sfx + e2);
        float r3 = interp1(acc, sfx + e3);
        nt_store4(orow + c * kChunk + lane * 4, r0, r1, r2, r3);

        running += total;
        if (running >= 63.0f) break;   // rest already filled by kernel A
    }
}

__global__ __launch_bounds__(256) void cope_tail_kernel(
    const float* __restrict__ query,
    const float* __restrict__ attn,
    const float* __restrict__ pos_emb,
    float* __restrict__ out)
{
    const int t    = threadIdx.x;
    const int lane = t & 63;
    const int wid  = t >> 6;
    const int row_base = blockIdx.x * kRowsPerBlock;
    const int h        = row_base >> 11;
    const int wrow = __builtin_amdgcn_readfirstlane(row_base + wid * 4);

    __shared__ float4 pe_lds[kNpos * 16];   // 16 KB, swizzled [n][j]

    const float* arow = attn + (size_t)wrow * kS;
    float*       orow = out  + (size_t)wrow * kS;

    // Prefetch rightmost attn chunk for all 4 rows (hides under stage+dot).
    const int tail = (kNChunks - 1) * kChunk + lane * 4;
    vfloat4 x0 = nt_load4(arow + 0 * kS + tail);
    vfloat4 x1 = nt_load4(arow + 1 * kS + tail);
    vfloat4 x2 = nt_load4(arow + 2 * kS + tail);
    vfloat4 x3 = nt_load4(arow + 3 * kS + tail);

    // Stage pe[h], swizzled: slot(n,j) = n*16 + (j ^ (n&15)).
    #pragma unroll
    for (int k = 0; k < 4; ++k) {
        const int e = t + 256 * k;       // float4 index in [0,1024)
        const int n = e >> 4;
        const int j = e & 15;
        float4 p = *reinterpret_cast<const float4*>(
            pos_emb + (size_t)n * kHid + h * kD + 4 * j);
        pe_lds[(n << 4) | (j ^ (n & 15))] = p;
    }
    __syncthreads();

    // 4-row dot; lane n = position n.
    const float* qbase = query + (size_t)wrow * kD;  // uniform -> s_load
    float acc0 = 0.f, acc1 = 0.f, acc2 = 0.f, acc3 = 0.f;
    #pragma unroll 4
    for (int j = 0; j < 16; ++j) {
        float4 pe4 = pe_lds[(lane << 4) | (j ^ (lane & 15))];
        const float* q0 = qbase + 0 * kD + 4 * j;
        const float* q1 = qbase + 1 * kD + 4 * j;
        const float* q2 = qbase + 2 * kD + 4 * j;
        const float* q3 = qbase + 3 * kD + 4 * j;
        acc0 += dot4f(pe4, q0[0], q0[1], q0[2], q0[3]);
        acc1 += dot4f(pe4, q1[0], q1[1], q1[2], q1[3]);
        acc2 += dot4f(pe4, q2[0], q2[1], q2[2], q2[3]);
        acc3 += dot4f(pe4, q3[0], q3[1], q3[2], q3[3]);
    }

    scan_row(arow + 0 * kS, orow + 0 * kS, acc0, x0, lane);
    scan_row(arow + 1 * kS, orow + 1 * kS, acc1, x1, lane);
    scan_row(arow + 2 * kS, orow + 2 * kS, acc2, x2, lane);
    scan_row(arow + 3 * kS, orow + 3 * kS, acc3, x3, lane);
}

extern "C" void kernel_launch(void* const* d_in, const int* in_sizes, int n_in,
                              void* d_out, int out_size, void* d_ws, size_t ws_size,
                              hipStream_t stream) {
    const float* query   = (const float*)d_in[0];
    const float* attn    = (const float*)d_in[1];
    const float* pos_emb = (const float*)d_in[2];
    float* out = (float*)d_out;

    const int rows = kH * kS;                    // 32768
    dim3 grid(rows / kRowsPerBlock), block(256); // 2048 blocks x 4 waves

    // Pure-write fill phase first (no DRAM turnarounds), then the small
    // mixed scan phase; tail overwrites fill leftward in the rare
    // un-clamped case (same stream -> ordered).
    cope_fill_kernel<<<grid, block, 0, stream>>>(query, pos_emb, out);
    cope_tail_kernel<<<grid, block, 0, stream>>>(query, attn, pos_emb, out);
}

// Round 10
// 57.781 us; speedup vs baseline: 1.0814x; 1.0814x over previous
//
#include <hip/hip_runtime.h>

namespace {
constexpr int kH       = 16;
constexpr int kS       = 2048;
constexpr int kD       = 64;
constexpr int kNpos    = 64;
constexpr int kHid     = 1024;  // H*D
constexpr int kChunk   = 256;   // 64 lanes * 4 floats
constexpr int kNChunks = kS / kChunk;    // 8
constexpr int kRowsPerBlock = 16;        // 4 waves * 4 rows
}

typedef float vfloat4 __attribute__((ext_vector_type(4)));

__device__ __forceinline__ float dot4f(float4 a, float qx, float qy, float qz, float qw) {
    return fmaf(a.x, qx, fmaf(a.y, qy, fmaf(a.z, qz, a.w * qw)));
}

template <int CTRL, int ROWM>
__device__ __forceinline__ float dpp_add(float v) {
    int t = __builtin_amdgcn_update_dpp(0, __float_as_int(v), CTRL, ROWM, 0xf, true);
    return v + __int_as_float(t);
}

// 64-lane inclusive prefix sum, pure VALU (classic GCN DPP scan).
__device__ __forceinline__ float wave_incl_scan(float v) {
    v = dpp_add<0x111, 0xf>(v);  // row_shr:1
    v = dpp_add<0x112, 0xf>(v);  // row_shr:2
    v = dpp_add<0x114, 0xf>(v);  // row_shr:4
    v = dpp_add<0x118, 0xf>(v);  // row_shr:8
    v = dpp_add<0x142, 0xa>(v);  // row_bcast15 -> rows 1,3
    v = dpp_add<0x143, 0xc>(v);  // row_bcast31 -> rows 2,3
    return v;
}

__device__ __forceinline__ float bcast_lane(float v, int l) {
    return __int_as_float(__builtin_amdgcn_readlane(__float_as_int(v), l));
}

__device__ __forceinline__ void nt_store4(float* p, float a, float b, float c, float d) {
    vfloat4 v = {a, b, c, d};
    __builtin_nontemporal_store(v, reinterpret_cast<vfloat4*>(p));
}
__device__ __forceinline__ vfloat4 nt_load4(const float* p) {
    return __builtin_nontemporal_load(reinterpret_cast<const vfloat4*>(p));
}

__device__ __forceinline__ float sigm(float v) {
    return 1.0f / (1.0f + __expf(-v));
}

// Interpolate one position value against the lane-held logits table.
__device__ __forceinline__ float interp1(float acc, float pin) {
    float pc = fminf(pin, 63.0f);
    float fl = floorf(pc);
    float w  = pc - fl;
    int  fi  = (int)fl;
    int  ni  = (fi < kNpos - 1) ? fi + 1 : kNpos - 1;
    float lf = __shfl(acc, fi);
    float ln = __shfl(acc, ni);
    return fmaf(w, ln - lf, lf);   // == lf when w==0
}

// Speculative constant fill of chunks 0..6 (compile-time unrolled burst).
// Correct regardless of data: the scan path below overwrites leftward
// (same thread -> same address -> program-ordered) wherever the cumsum
// hasn't clamped.
__device__ __forceinline__ void fill_row(float* __restrict__ orow,
                                         float fill, int lane) {
    #pragma unroll
    for (int j = 0; j < kNChunks - 1; ++j) {
        nt_store4(orow + j * kChunk + lane * 4, fill, fill, fill, fill);
    }
}

// Scan + interpolate + store, rightmost chunk first; continue leftward
// (overwriting the speculative fill) only while running < 63.
__device__ __forceinline__ void scan_row(const float* __restrict__ arow,
                                         float* __restrict__ orow,
                                         float acc, vfloat4 x0, int lane) {
    float running = 0.0f;
    vfloat4 x = x0;
    for (int c = kNChunks - 1; c >= 0; --c) {
        if (c != kNChunks - 1)
            x = nt_load4(arow + c * kChunk + lane * 4);
        float g0 = sigm(x.x), g1 = sigm(x.y);
        float g2 = sigm(x.z), g3 = sigm(x.w);

        float e3 = g3;
        float e2 = e3 + g2;
        float e1 = e2 + g1;
        float e0 = e1 + g0;          // lane total

        float incl  = wave_incl_scan(e0);
        float total = bcast_lane(incl, 63);
        float sfx   = running + (total - incl);

        float r0 = interp1(acc, sfx + e0);
        float r1 = interp1(acc, sfx + e1);
        float r2 = interp1(acc, sfx + e2);
        float r3 = interp1(acc, sfx + e3);
        nt_store4(orow + c * kChunk + lane * 4, r0, r1, r2, r3);

        running += total;
        if (running >= 63.0f) break;   // rest already filled speculatively
    }
}

// Block = 16 consecutive rows (same head). Wave = 4 rows.
// Phase 0: stage pe[h] (16 KB) into LDS, XOR-swizzled float4 layout.
// Phase 1: lane n computes logits_int[n] for 4 rows (ds_read_b128 amortized).
// Phase 2: speculative fill burst for all 4 rows (28 unrolled nt stores,
//          issued before any scan compute), then per-row scan of the
//          rightmost chunk with rare leftward continuation.
__global__ __launch_bounds__(256) void cope_kernel(
    const float* __restrict__ query,
    const float* __restrict__ attn,
    const float* __restrict__ pos_emb,
    float* __restrict__ out)
{
    const int t    = threadIdx.x;
    const int lane = t & 63;
    const int wid  = t >> 6;
    const int row_base = blockIdx.x * kRowsPerBlock;
    const int h        = row_base >> 11;           // row / S
    const int wrow = __builtin_amdgcn_readfirstlane(row_base + wid * 4);

    __shared__ float4 pe_lds[kNpos * 16];          // 16 KB, swizzled [n][j]

    const float* arow = attn + (size_t)wrow * kS;
    float*       orow = out  + (size_t)wrow * kS;

    // Prefetch rightmost attn chunk for all 4 rows (hides under stage+dot).
    const int tail = (kNChunks - 1) * kChunk + lane * 4;
    vfloat4 x0 = nt_load4(arow + 0 * kS + tail);
    vfloat4 x1 = nt_load4(arow + 1 * kS + tail);
    vfloat4 x2 = nt_load4(arow + 2 * kS + tail);
    vfloat4 x3 = nt_load4(arow + 3 * kS + tail);

    // ---- Phase 0: stage pe[h], swizzled: slot(n,j) = n*16 + (j ^ (n&15)) ----
    #pragma unroll
    for (int k = 0; k < 4; ++k) {
        const int e = t + 256 * k;       // float4 index in [0,1024)
        const int n = e >> 4;
        const int j = e & 15;
        float4 p = *reinterpret_cast<const float4*>(
            pos_emb + (size_t)n * kHid + h * kD + 4 * j);
        pe_lds[(n << 4) | (j ^ (n & 15))] = p;
    }
    __syncthreads();

    // ---- Phase 1: 4-row dot; lane n = position n ----
    const float* qbase = query + (size_t)wrow * kD;  // uniform -> s_load
    float acc0 = 0.f, acc1 = 0.f, acc2 = 0.f, acc3 = 0.f;
    #pragma unroll 4
    for (int j = 0; j < 16; ++j) {
        float4 pe4 = pe_lds[(lane << 4) | (j ^ (lane & 15))];
        const float* q0 = qbase + 0 * kD + 4 * j;
        const float* q1 = qbase + 1 * kD + 4 * j;
        const float* q2 = qbase + 2 * kD + 4 * j;
        const float* q3 = qbase + 3 * kD + 4 * j;
        acc0 += dot4f(pe4, q0[0], q0[1], q0[2], q0[3]);
        acc1 += dot4f(pe4, q1[0], q1[1], q1[2], q1[3]);
        acc2 += dot4f(pe4, q2[0], q2[1], q2[2], q2[3]);
        acc3 += dot4f(pe4, q3[0], q3[1], q3[2], q3[3]);
    }

    // ---- Phase 2a: speculative fill burst (7/8 of all bytes), issued
    //      before any scan compute so the store stream never waits. ----
    fill_row(orow + 0 * kS, bcast_lane(acc0, kNpos - 1), lane);
    fill_row(orow + 1 * kS, bcast_lane(acc1, kNpos - 1), lane);
    fill_row(orow + 2 * kS, bcast_lane(acc2, kNpos - 1), lane);
    fill_row(orow + 3 * kS, bcast_lane(acc3, kNpos - 1), lane);

    // ---- Phase 2b: scan + interpolate the rightmost chunk per row ----
    scan_row(arow + 0 * kS, orow + 0 * kS, acc0, x0, lane);
    scan_row(arow + 1 * kS, orow + 1 * kS, acc1, x1, lane);
    scan_row(arow + 2 * kS, orow + 2 * kS, acc2, x2, lane);
    scan_row(arow + 3 * kS, orow + 3 * kS, acc3, x3, lane);
}

extern "C" void kernel_launch(void* const* d_in, const int* in_sizes, int n_in,
                              void* d_out, int out_size, void* d_ws, size_t ws_size,
                              hipStream_t stream) {
    const float* query   = (const float*)d_in[0];
    const float* attn    = (const float*)d_in[1];
    const float* pos_emb = (const float*)d_in[2];
    float* out = (float*)d_out;

    const int rows = kH * kS;                    // 32768
    dim3 grid(rows / kRowsPerBlock), block(256); // 2048 blocks x 4 waves
    cope_kernel<<<grid, block, 0, stream>>>(query, attn, pos_emb, out);
}